// Round 3
// baseline (1042.364 us; speedup 1.0000x reference)
//
#include <hip/hip_runtime.h>

// Problem constants
#define NB   4
#define SEQ  1024
#define DIM  512
#define NH   8
#define HD   64
#define MLPD 2048
#define NL   4
#define TOPKK 256
#define QKVD 1536   // 3*DIM
#define QT   16     // queries per attention block

typedef short bh8 __attribute__((ext_vector_type(8)));
typedef float f32x4 __attribute__((ext_vector_type(4)));

// ---------- helpers ----------
__device__ __forceinline__ float b2f(unsigned short v) {
    return __uint_as_float(((unsigned)v) << 16);
}
__device__ __forceinline__ unsigned short f2b(float f) {
    unsigned u = __float_as_uint(f);
    u += 0x7FFFu + ((u >> 16) & 1u);   // RNE
    return (unsigned short)(u >> 16);
}
__device__ __forceinline__ float ldin(const void* p, size_t i, int bf) {
    return bf ? b2f(((const unsigned short*)p)[i]) : ((const float*)p)[i];
}
__device__ __forceinline__ float wave_sum(float v) {
#pragma unroll
    for (int m = 32; m; m >>= 1) v += __shfl_xor(v, m);
    return v;
}
// monotone bf16-bits -> 16-bit radix key, and inverse
__device__ __forceinline__ unsigned f2key16(unsigned short u) {
    return (u & 0x8000u) ? (unsigned)((~u) & 0xFFFFu) : (unsigned)(u | 0x8000u);
}
__device__ __forceinline__ unsigned short key16b(unsigned k) {
    return (k & 0x8000u) ? (unsigned short)(k & 0x7FFFu)
                         : (unsigned short)((~k) & 0xFFFFu);
}
// 8 contiguous fp32 -> packed bf16x8
__device__ __forceinline__ uint4 pack8(const float* __restrict__ p) {
    uint4 r;
    r.x = (unsigned)f2b(p[0]) | ((unsigned)f2b(p[1]) << 16);
    r.y = (unsigned)f2b(p[2]) | ((unsigned)f2b(p[3]) << 16);
    r.z = (unsigned)f2b(p[4]) | ((unsigned)f2b(p[5]) << 16);
    r.w = (unsigned)f2b(p[6]) | ((unsigned)f2b(p[7]) << 16);
    return r;
}
// async 16B/lane global->LDS: LDS dest = wave-uniform base + lane*16
__device__ __forceinline__ void async16(unsigned short* lds, const unsigned short* g) {
    __builtin_amdgcn_global_load_lds(
        (const __attribute__((address_space(1))) unsigned int*)g,
        (__attribute__((address_space(3))) unsigned int*)lds, 16, 0, 0);
}

// ---------- kernels ----------

__global__ void detect_kernel(const unsigned short* __restrict__ ln1w,
                              int* __restrict__ flag) {
    if (threadIdx.x == 0 && blockIdx.x == 0)
        *flag = (ln1w[0] == 0x3F80u) ? 1 : 0;
}

// convert weight array (input dtype) -> bf16 scratch
__global__ __launch_bounds__(256) void wcvt_kernel(
    const void* __restrict__ W, unsigned short* __restrict__ out,
    int n, const int* __restrict__ dflag) {
    int bf = *dflag;
    int idx = blockIdx.x * 256 + threadIdx.x;
    if (idx < n) out[idx] = f2b(ldin(W, idx, bf));
}

__global__ __launch_bounds__(256) void addpos_kernel(
    const void* __restrict__ x, const void* __restrict__ pos,
    float* __restrict__ h, const int* __restrict__ dflag) {
    int bf = *dflag;
    int idx = blockIdx.x * 256 + threadIdx.x;
    int sd = idx & (SEQ * DIM - 1);
    h[idx] = ldin(x, idx, bf) + ldin(pos, sd, bf);
}

// layernorm over last dim (512): fp32 in, bf16 out. w/b at element offset wo.
__global__ __launch_bounds__(256) void ln_kernel(
    const float* __restrict__ in, const void* __restrict__ w,
    const void* __restrict__ bb, size_t wo, unsigned short* __restrict__ out,
    const int* __restrict__ dflag) {
    int bf = *dflag;
    __shared__ float red[4];
    int row = blockIdx.x, tid = threadIdx.x;
    int lane = tid & 63, wid = tid >> 6;
    const float* p = in + (size_t)row * DIM;
    float x0 = p[tid], x1 = p[tid + 256];
    float s = wave_sum(x0 + x1);
    if (!lane) red[wid] = s;
    __syncthreads();
    float mean = (red[0] + red[1] + red[2] + red[3]) * (1.0f / DIM);
    float d0 = x0 - mean, d1 = x1 - mean;
    float q = wave_sum(d0 * d0 + d1 * d1);
    __syncthreads();
    if (!lane) red[wid] = q;
    __syncthreads();
    float var = (red[0] + red[1] + red[2] + red[3]) * (1.0f / DIM);
    float rs = rsqrtf(var + 1e-6f);
    unsigned short* o = out + (size_t)row * DIM;
    o[tid]       = f2b(d0 * rs * ldin(w, wo + tid, bf) + ldin(bb, wo + tid, bf));
    o[tid + 256] = f2b(d1 * rs * ldin(w, wo + tid + 256, bf) + ldin(bb, wo + tid + 256, bf));
}

// final layernorm: fp32 in, output in detected dtype
__global__ __launch_bounds__(256) void lnf_kernel(
    const float* __restrict__ in, const void* __restrict__ w,
    const void* __restrict__ bb, void* __restrict__ out,
    const int* __restrict__ dflag) {
    int bf = *dflag;
    __shared__ float red[4];
    int row = blockIdx.x, tid = threadIdx.x;
    int lane = tid & 63, wid = tid >> 6;
    const float* p = in + (size_t)row * DIM;
    float x0 = p[tid], x1 = p[tid + 256];
    float s = wave_sum(x0 + x1);
    if (!lane) red[wid] = s;
    __syncthreads();
    float mean = (red[0] + red[1] + red[2] + red[3]) * (1.0f / DIM);
    float d0 = x0 - mean, d1 = x1 - mean;
    float q = wave_sum(d0 * d0 + d1 * d1);
    __syncthreads();
    if (!lane) red[wid] = q;
    __syncthreads();
    float var = (red[0] + red[1] + red[2] + red[3]) * (1.0f / DIM);
    float rs = rsqrtf(var + 1e-6f);
    float v0 = d0 * rs * ldin(w, tid, bf) + ldin(bb, tid, bf);
    float v1 = d1 * rs * ldin(w, tid + 256, bf) + ldin(bb, tid + 256, bf);
    size_t o = (size_t)row * DIM;
    if (bf) {
        ((unsigned short*)out)[o + tid]       = f2b(v0);
        ((unsigned short*)out)[o + tid + 256] = f2b(v1);
    } else {
        ((float*)out)[o + tid]       = v0;
        ((float*)out)[o + tid + 256] = v1;
    }
}

// ---- fallback GEMMs (inline fp32->bf16 pack) ----
__global__ __launch_bounds__(256) void gemm_mfma_kernel(
    const unsigned short* __restrict__ A, const void* __restrict__ W, size_t wo,
    const void* __restrict__ bias, size_t bo, void* __restrict__ C,
    int M, int N, int K, int flags, const int* __restrict__ dflag) {
    int bf = *dflag;
    __shared__ unsigned short As[128 * 32];
    __shared__ unsigned short Bs[128 * 32];
    int tid = threadIdx.x;
    int w = tid >> 6, l = tid & 63;
    int n0 = blockIdx.x * 128, m0 = blockIdx.y * 128;
    int wm = (w >> 1) * 64, wn = (w & 1) * 64;
    int lq = l & 15, lk = l >> 4;

    int srow = w * 32 + (l >> 2);
    int cb = (l & 3) * 8;
    const unsigned short* aG = A + (size_t)(m0 + srow) * K + cb;
    size_t wb = wo + (size_t)(n0 + srow) * K + cb;
    unsigned short* sA0 = &As[w * 1024 + l * 8];
    unsigned short* sA1 = &As[w * 1024 + 512 + l * 8];
    unsigned short* sB0 = &Bs[w * 1024 + l * 8];
    unsigned short* sB1 = &Bs[w * 1024 + 512 + l * 8];

    f32x4 acc[4][4];
#pragma unroll
    for (int i = 0; i < 4; ++i)
#pragma unroll
        for (int j = 0; j < 4; ++j)
            acc[i][j] = (f32x4){0.f, 0.f, 0.f, 0.f};

    for (int k0 = 0; k0 < K; k0 += 32) {
        uint4 a0 = *(const uint4*)(aG + k0);
        uint4 a1 = *(const uint4*)(aG + 16 * K + k0);
        uint4 b0, b1;
        if (bf) {
            b0 = *(const uint4*)((const unsigned short*)W + wb + k0);
            b1 = *(const uint4*)((const unsigned short*)W + wb + 16 * K + k0);
        } else {
            b0 = pack8((const float*)W + wb + k0);
            b1 = pack8((const float*)W + wb + 16 * K + k0);
        }
        __syncthreads();
        *(uint4*)sA0 = a0;
        *(uint4*)sA1 = a1;
        *(uint4*)sB0 = b0;
        *(uint4*)sB1 = b1;
        __syncthreads();
        bh8 af[4], bw[4];
#pragma unroll
        for (int i = 0; i < 4; ++i) {
            af[i] = *(const bh8*)&As[(wm + i * 16 + lq) * 32 + lk * 8];
            bw[i] = *(const bh8*)&Bs[(wn + i * 16 + lq) * 32 + lk * 8];
        }
#pragma unroll
        for (int i = 0; i < 4; ++i)
#pragma unroll
            for (int j = 0; j < 4; ++j)
                acc[i][j] = __builtin_amdgcn_mfma_f32_16x16x32_bf16(
                    af[i], bw[j], acc[i][j], 0, 0, 0);
    }

    int lr4 = lk * 4;
#pragma unroll
    for (int i = 0; i < 4; ++i) {
#pragma unroll
        for (int j = 0; j < 4; ++j) {
            int n = n0 + wn + j * 16 + lq;
            float bv = (flags & 4) ? ldin(bias, bo + n, bf) : 0.0f;
#pragma unroll
            for (int r = 0; r < 4; ++r) {
                int m = m0 + wm + i * 16 + lr4 + r;
                float v = acc[i][j][r] + bv;
                if (flags & 2) v = 0.5f * v * (1.0f + erff(v * 0.70710678118654752f));
                size_t o = (size_t)m * N + n;
                if (flags & 1) ((float*)C)[o] += v;
                else           ((unsigned short*)C)[o] = f2b(v);
            }
        }
    }
}

__global__ __launch_bounds__(256) void gemm_mfma_n64_kernel(
    const unsigned short* __restrict__ A, const void* __restrict__ W, size_t wo,
    const void* __restrict__ bias, size_t bo, void* __restrict__ C,
    int M, int N, int K, int flags, const int* __restrict__ dflag) {
    int bf = *dflag;
    __shared__ unsigned short As[128 * 32];
    __shared__ unsigned short Bs[64 * 32];
    int tid = threadIdx.x;
    int w = tid >> 6, l = tid & 63;
    int n0 = blockIdx.x * 64, m0 = blockIdx.y * 128;
    int wm = (w >> 1) * 64, wn = (w & 1) * 32;
    int lq = l & 15, lk = l >> 4;

    int srowA = w * 32 + (l >> 2);
    int cb = (l & 3) * 8;
    const unsigned short* aG = A + (size_t)(m0 + srowA) * K + cb;
    int srowB = w * 16 + (l >> 2);
    size_t wb = wo + (size_t)(n0 + srowB) * K + cb;
    unsigned short* sA0 = &As[w * 1024 + l * 8];
    unsigned short* sA1 = &As[w * 1024 + 512 + l * 8];
    unsigned short* sB0 = &Bs[w * 512 + l * 8];

    f32x4 acc[4][2];
#pragma unroll
    for (int i = 0; i < 4; ++i) {
        acc[i][0] = (f32x4){0.f, 0.f, 0.f, 0.f};
        acc[i][1] = (f32x4){0.f, 0.f, 0.f, 0.f};
    }

    for (int k0 = 0; k0 < K; k0 += 32) {
        uint4 a0 = *(const uint4*)(aG + k0);
        uint4 a1 = *(const uint4*)(aG + 16 * K + k0);
        uint4 b0;
        if (bf) b0 = *(const uint4*)((const unsigned short*)W + wb + k0);
        else    b0 = pack8((const float*)W + wb + k0);
        __syncthreads();
        *(uint4*)sA0 = a0;
        *(uint4*)sA1 = a1;
        *(uint4*)sB0 = b0;
        __syncthreads();
        bh8 af[4], bw[2];
#pragma unroll
        for (int i = 0; i < 4; ++i)
            af[i] = *(const bh8*)&As[(wm + i * 16 + lq) * 32 + lk * 8];
        bw[0] = *(const bh8*)&Bs[(wn + lq) * 32 + lk * 8];
        bw[1] = *(const bh8*)&Bs[(wn + 16 + lq) * 32 + lk * 8];
#pragma unroll
        for (int i = 0; i < 4; ++i) {
            acc[i][0] = __builtin_amdgcn_mfma_f32_16x16x32_bf16(af[i], bw[0], acc[i][0], 0, 0, 0);
            acc[i][1] = __builtin_amdgcn_mfma_f32_16x16x32_bf16(af[i], bw[1], acc[i][1], 0, 0, 0);
        }
    }

    int lr4 = lk * 4;
#pragma unroll
    for (int i = 0; i < 4; ++i) {
#pragma unroll
        for (int j = 0; j < 2; ++j) {
            int n = n0 + wn + j * 16 + lq;
            float bv = (flags & 4) ? ldin(bias, bo + n, bf) : 0.0f;
#pragma unroll
            for (int r = 0; r < 4; ++r) {
                int m = m0 + wm + i * 16 + lr4 + r;
                float v = acc[i][j][r] + bv;
                if (flags & 2) v = 0.5f * v * (1.0f + erff(v * 0.70710678118654752f));
                size_t o = (size_t)m * N + n;
                if (flags & 1) ((float*)C)[o] += v;
                else           ((unsigned short*)C)[o] = f2b(v);
            }
        }
    }
}

// ---- main-path GEMM: 128Mx64N, bf16 weights, global_load_lds staging,
// optional split-K via blockIdx.z (flags&8 = atomic fp32 +=).
// flags: 1 = plain fp32 +=, 2 = GELU->bf16, 0 = bf16 store, 4 = bias, 8 = atomic +=
__global__ __launch_bounds__(256) void gemm_n64_dlds_kernel(
    const unsigned short* __restrict__ A, const unsigned short* __restrict__ W, size_t wo,
    const void* __restrict__ bias, size_t bo, void* __restrict__ C,
    int M, int N, int K, int flags, const int* __restrict__ dflag) {
    __shared__ unsigned short As[128 * 32];
    __shared__ unsigned short Bs[64 * 32];
    int tid = threadIdx.x;
    int w = tid >> 6, l = tid & 63;
    int n0 = blockIdx.x * 64, m0 = blockIdx.y * 128;
    int kz = blockIdx.z;
    int Ks = K / (int)gridDim.z;
    int kbeg = kz * Ks, kend = kbeg + Ks;
    int wm = (w >> 1) * 64, wn = (w & 1) * 32;
    int lq = l & 15, lk = l >> 4;

    int srowA = w * 32 + (l >> 2);
    int srowB = w * 16 + (l >> 2);
    int cb = (l & 3) * 8;
    const unsigned short* aG = A + (size_t)(m0 + srowA) * K + cb;
    const unsigned short* wG = W + wo + (size_t)(n0 + srowB) * K + cb;
    unsigned short* lA0 = As + w * 1024;
    unsigned short* lA1 = As + w * 1024 + 512;
    unsigned short* lB0 = Bs + w * 512;

    f32x4 acc[4][2];
#pragma unroll
    for (int i = 0; i < 4; ++i) {
        acc[i][0] = (f32x4){0.f, 0.f, 0.f, 0.f};
        acc[i][1] = (f32x4){0.f, 0.f, 0.f, 0.f};
    }

    for (int k0 = kbeg; k0 < kend; k0 += 32) {
        __syncthreads();            // prior iter's LDS reads complete
        async16(lA0, aG + k0);
        async16(lA1, aG + 16 * K + k0);
        async16(lB0, wG + k0);
        __syncthreads();            // barrier drains vmcnt -> staged
        bh8 af[4], bw[2];
#pragma unroll
        for (int i = 0; i < 4; ++i)
            af[i] = *(const bh8*)&As[(wm + i * 16 + lq) * 32 + lk * 8];
        bw[0] = *(const bh8*)&Bs[(wn + lq) * 32 + lk * 8];
        bw[1] = *(const bh8*)&Bs[(wn + 16 + lq) * 32 + lk * 8];
#pragma unroll
        for (int i = 0; i < 4; ++i) {
            acc[i][0] = __builtin_amdgcn_mfma_f32_16x16x32_bf16(af[i], bw[0], acc[i][0], 0, 0, 0);
            acc[i][1] = __builtin_amdgcn_mfma_f32_16x16x32_bf16(af[i], bw[1], acc[i][1], 0, 0, 0);
        }
    }

    int bf = (flags & 4) ? *dflag : 0;
    int lr4 = lk * 4;
#pragma unroll
    for (int i = 0; i < 4; ++i) {
#pragma unroll
        for (int j = 0; j < 2; ++j) {
            int n = n0 + wn + j * 16 + lq;
            float bv = ((flags & 4) && kz == 0) ? ldin(bias, bo + n, bf) : 0.0f;
#pragma unroll
            for (int r = 0; r < 4; ++r) {
                int m = m0 + wm + i * 16 + lr4 + r;
                float v = acc[i][j][r] + bv;
                if (flags & 2) v = 0.5f * v * (1.0f + erff(v * 0.70710678118654752f));
                size_t o = (size_t)m * N + n;
                if (flags & 8)      atomicAdd(&((float*)C)[o], v);
                else if (flags & 1) ((float*)C)[o] += v;
                else                ((unsigned short*)C)[o] = f2b(v);
            }
        }
    }
}

// ---- 128Mx128N variant (qkv / mlp1): 16 MFMA per 4 staged loads per wave ----
__global__ __launch_bounds__(256) void gemm_n128_dlds_kernel(
    const unsigned short* __restrict__ A, const unsigned short* __restrict__ W, size_t wo,
    const void* __restrict__ bias, size_t bo, void* __restrict__ C,
    int M, int N, int K, int flags, const int* __restrict__ dflag) {
    __shared__ unsigned short As[128 * 32];
    __shared__ unsigned short Bs[128 * 32];
    int tid = threadIdx.x;
    int w = tid >> 6, l = tid & 63;
    int n0 = blockIdx.x * 128, m0 = blockIdx.y * 128;
    int wm = (w >> 1) * 64, wn = (w & 1) * 64;
    int lq = l & 15, lk = l >> 4;

    int srow = w * 32 + (l >> 2);
    int cb = (l & 3) * 8;
    const unsigned short* aG = A + (size_t)(m0 + srow) * K + cb;
    const unsigned short* wG = W + wo + (size_t)(n0 + srow) * K + cb;
    unsigned short* lA0 = As + w * 1024;
    unsigned short* lA1 = As + w * 1024 + 512;
    unsigned short* lB0 = Bs + w * 1024;
    unsigned short* lB1 = Bs + w * 1024 + 512;

    f32x4 acc[4][4];
#pragma unroll
    for (int i = 0; i < 4; ++i)
#pragma unroll
        for (int j = 0; j < 4; ++j)
            acc[i][j] = (f32x4){0.f, 0.f, 0.f, 0.f};

    for (int k0 = 0; k0 < K; k0 += 32) {
        __syncthreads();
        async16(lA0, aG + k0);
        async16(lA1, aG + 16 * K + k0);
        async16(lB0, wG + k0);
        async16(lB1, wG + 16 * K + k0);
        __syncthreads();
        bh8 af[4], bw[4];
#pragma unroll
        for (int i = 0; i < 4; ++i) {
            af[i] = *(const bh8*)&As[(wm + i * 16 + lq) * 32 + lk * 8];
            bw[i] = *(const bh8*)&Bs[(wn + i * 16 + lq) * 32 + lk * 8];
        }
#pragma unroll
        for (int i = 0; i < 4; ++i)
#pragma unroll
            for (int j = 0; j < 4; ++j)
                acc[i][j] = __builtin_amdgcn_mfma_f32_16x16x32_bf16(
                    af[i], bw[j], acc[i][j], 0, 0, 0);
    }

    int bf = (flags & 4) ? *dflag : 0;
    int lr4 = lk * 4;
#pragma unroll
    for (int i = 0; i < 4; ++i) {
#pragma unroll
        for (int j = 0; j < 4; ++j) {
            int n = n0 + wn + j * 16 + lq;
            float bv = (flags & 4) ? ldin(bias, bo + n, bf) : 0.0f;
#pragma unroll
            for (int r = 0; r < 4; ++r) {
                int m = m0 + wm + i * 16 + lr4 + r;
                float v = acc[i][j][r] + bv;
                if (flags & 2) v = 0.5f * v * (1.0f + erff(v * 0.70710678118654752f));
                size_t o = (size_t)m * N + n;
                if (flags & 1) ((float*)C)[o] += v;
                else           ((unsigned short*)C)[o] = f2b(v);
            }
        }
    }
}

// fused depthwise conv (k=3 along s) + q/k normalize + scatter.
// reads qkv (B,S,3D) bf16 pre-conv; writes: qn (B,S,D bf16, temp folded),
// Kc[bh][s][c], Vt[bh][s>>5][c][s&31]. No aliasing with input.
__global__ __launch_bounds__(256) void dwqkv_kernel(
    const unsigned short* __restrict__ in, const void* __restrict__ w, size_t wo,
    const void* __restrict__ temp, size_t to,
    unsigned short* __restrict__ qn, unsigned short* __restrict__ Kc,
    unsigned short* __restrict__ Vt, const int* __restrict__ dflag) {
    int bf = *dflag;
    int tid = threadIdx.x;
    int g = tid >> 6, c = tid & 63;
    int gid = blockIdx.x * 4 + g;          // (b*S+s)*H + h
    int h = gid & 7;
    int bs = gid >> 3;
    int s = bs & (SEQ - 1), b = bs >> 10;
    int bh = b * NH + h;
    const unsigned short* row = in + (size_t)bs * QKVD;
    float vals[3];
#pragma unroll
    for (int t = 0; t < 3; ++t) {
        int o = t * 512 + h * HD + c;
        float w0 = ldin(w, wo + o * 3 + 0, bf);
        float w1 = ldin(w, wo + o * 3 + 1, bf);
        float w2 = ldin(w, wo + o * 3 + 2, bf);
        float a = w1 * b2f(row[o]);
        if (s > 0)       a += w0 * b2f(row[o - QKVD]);
        if (s < SEQ - 1) a += w2 * b2f(row[o + QKVD]);
        vals[t] = a;
    }
    float qs = wave_sum(vals[0] * vals[0]);
    float ks = wave_sum(vals[1] * vals[1]);
    float t_ = ldin(temp, to + h, bf);
    qn[(size_t)bs * DIM + h * HD + c] = f2b(vals[0] / fmaxf(sqrtf(qs), 1e-12f) * t_);
    Kc[((size_t)bh * SEQ + s) * HD + c] = f2b(vals[1] / fmaxf(sqrtf(ks), 1e-12f));
    Vt[(((size_t)bh * 32 + (s >> 5)) * HD + c) * 32 + (s & 31)] = f2b(vals[2]);
}

// Q-tiled MFMA attention.
// v4: XCD-locality block remap. Round-robin dispatch sends bid -> XCD (bid&7);
// decode so all 64 q-tiles of one (b,h) share bid&7 => same XCD L2 holds that
// group's K+V (256KB) + q slice (~1.5MB/XCD total, fits 4MB L2). Bijective.
__global__ __launch_bounds__(256) void attn_kernel(
    const unsigned short* __restrict__ q, const unsigned short* __restrict__ Kc,
    const unsigned short* __restrict__ Vt, unsigned short* __restrict__ outp) {
    __shared__ __align__(16) unsigned short sc16[QT * 1024];

    int tid = threadIdx.x;
    int w = tid >> 6, l = tid & 63;
    int lq = l & 15, lk = l >> 4;
    int bid = blockIdx.x;
    int qt = (bid >> 3) & 63;
    int bh = ((bid >> 9) << 3) | (bid & 7);   // (slot>>6)*8 + xcd
    int h = bh & 7;
    int b = bh >> 3;

    // q rows have stride DIM (written by dwqkv into a dense (B*S, D) buffer)
    const unsigned short* qp = q + (size_t)(b * SEQ + qt * QT + lq) * DIM + h * HD + lk * 8;
    bh8 aq0 = *(const bh8*)(qp);
    bh8 aq1 = *(const bh8*)(qp + 32);

    // QK^T: wave w computes keys [w*256,(w+1)*256) for all 16 queries
    const unsigned short* Kbh = Kc + (size_t)bh * SEQ * HD;
    int wi = lq & 7;
    for (int kb = 0; kb < 16; ++kb) {
        int key0 = (w * 16 + kb) * 16;
        const unsigned short* kp = Kbh + (size_t)(key0 + lq) * HD + lk * 8;
        bh8 b0 = *(const bh8*)(kp);
        bh8 b1 = *(const bh8*)(kp + 32);
        f32x4 acc = {0.f, 0.f, 0.f, 0.f};
        acc = __builtin_amdgcn_mfma_f32_16x16x32_bf16(aq0, b0, acc, 0, 0, 0);
        acc = __builtin_amdgcn_mfma_f32_16x16x32_bf16(aq1, b1, acc, 0, 0, 0);
        int chunk = (key0 + lq) >> 3;
#pragma unroll
        for (int r = 0; r < 4; ++r) {
            int row = lk * 4 + r;
            int sw = (row ^ (row >> 2)) & 7;
            sc16[row * 1024 + ((chunk ^ sw) << 3) + wi] = f2b(acc[r]);
        }
    }
    __syncthreads();

    // fused top-k select + softmax: wave w owns rows w*4..w*4+3
    for (int rr = 0; rr < 4; ++rr) {
        int row = w * 4 + rr;
        unsigned short* srow = sc16 + row * 1024;
        uint4 r0 = *(const uint4*)&srow[l * 8];
        uint4 r1 = *(const uint4*)&srow[512 + l * 8];
        unsigned wd[8] = {r0.x, r0.y, r0.z, r0.w, r1.x, r1.y, r1.z, r1.w};
        float v[16];
#pragma unroll
        for (int j = 0; j < 8; ++j) {
            v[2 * j]     = __uint_as_float(wd[j] << 16);
            v[2 * j + 1] = __uint_as_float(wd[j] & 0xFFFF0000u);
        }
        // row max (order-independent under swizzle)
        float m = v[0];
#pragma unroll
        for (int j = 1; j < 16; ++j) m = fmaxf(m, v[j]);
#pragma unroll
        for (int off = 1; off < 64; off <<= 1) m = fmaxf(m, __shfl_xor(m, off));
        m = fminf(fmaxf(m, -10000.f), 10000.f);
        // ballot binary search for kth-largest bf16 value (exact tie semantics)
        unsigned T = 0;
        for (int bit = 15; bit >= 0; --bit) {
            unsigned cand = T | (1u << bit);
            float tf = b2f(key16b(cand));
            unsigned cnt = 0;
#pragma unroll
            for (int j = 0; j < 16; ++j)
                cnt += (unsigned)__popcll(__ballot(v[j] >= tf));
            if (cnt >= TOPKK) T = cand;
        }
        float kth = b2f(key16b(T));
        // exp + sum (excluded -> exactly 0.0f)
        float ssum = 0.f;
#pragma unroll
        for (int j = 0; j < 16; ++j) {
            float a = fminf(fmaxf(v[j], -10000.f), 10000.f);
            float ev = (v[j] >= kth) ? __expf(a - m) : 0.0f;
            ssum += ev;
            v[j] = ev;
        }
#pragma unroll
        for (int off = 1; off < 64; off <<= 1) ssum += __shfl_xor(ssum, off);
        float inv = 1.0f / ssum;
        // pre-scale by 1/sum, pack to bf16 (HW RNE), write back in place
        unsigned pw[8];
#pragma unroll
        for (int j = 0; j < 8; ++j) {
            float e0 = v[2 * j] * inv, e1 = v[2 * j + 1] * inv;
            unsigned r;
            asm("v_cvt_pk_bf16_f32 %0, %1, %2" : "=v"(r) : "v"(e0), "v"(e1));
            pw[j] = r;
        }
        *(uint4*)&srow[l * 8]       = (uint4){pw[0], pw[1], pw[2], pw[3]};
        *(uint4*)&srow[512 + l * 8] = (uint4){pw[4], pw[5], pw[6], pw[7]};
    }
    __syncthreads();

    // PV (P already normalized)
    {
        const unsigned short* Vbh = Vt + (size_t)bh * SEQ * HD;
        const unsigned short* prow = sc16 + lq * 1024;
        int swq = (lq ^ (lq >> 2)) & 7;
        f32x4 oacc = {0.f, 0.f, 0.f, 0.f};
        for (int tc = 0; tc < 32; ++tc) {
            bh8 ap = *(const bh8*)&prow[((tc * 4 + lk) ^ swq) << 3];
            bh8 bv = *(const bh8*)(Vbh + (size_t)tc * 2048 + (w * 16 + lq) * 32 + lk * 8);
            oacc = __builtin_amdgcn_mfma_f32_16x16x32_bf16(ap, bv, oacc, 0, 0, 0);
        }
#pragma unroll
        for (int r = 0; r < 4; ++r) {
            int qrow = lk * 4 + r;
            outp[((size_t)(b * SEQ + qt * QT + qrow)) * DIM + h * HD + w * 16 + lq] = f2b(oacc[r]);
        }
    }
}

// ---------- host ----------
extern "C" void kernel_launch(void* const* d_in, const int* in_sizes, int n_in,
                              void* d_out, int out_size, void* d_ws, size_t ws_size,
                              hipStream_t stream) {
    (void)in_sizes; (void)n_in; (void)out_size;
    const void* x     = d_in[0];
    const void* pos   = d_in[1];
    const void* ln1w  = d_in[2];
    const void* ln1b  = d_in[3];
    const void* qkvw  = d_in[4];
    const void* dww   = d_in[5];
    const void* temp  = d_in[6];
    const void* projw = d_in[7];
    const void* ln2w  = d_in[8];
    const void* ln2b  = d_in[9];
    const void* w1    = d_in[10];
    const void* b1    = d_in[11];
    const void* w2    = d_in[12];
    const void* b2    = d_in[13];
    const void* lnfw  = d_in[14];
    const void* lnfb  = d_in[15];

    // ws layout (float units): h[0,2M) | bn@2M (ln out / q / attn out) |
    // C2@3M (qkv pre-conv / MLP mid) | Vt@6M | Kc@7M | flag@9M | Wc@(9M+16)
    float* wsf = (float*)d_ws;
    const size_t M1 = (size_t)1024 * 1024;
    float*          h    = wsf;
    unsigned short* bn   = (unsigned short*)(wsf + 2 * M1);
    unsigned short* C2   = (unsigned short*)(wsf + 3 * M1);
    unsigned short* Vt   = (unsigned short*)(wsf + 6 * M1);
    unsigned short* Kc   = (unsigned short*)(wsf + 7 * M1);
    unsigned short* Mb   = C2;
    int*            flag = (int*)(wsf + 9 * M1);
    unsigned short* Wc   = (unsigned short*)(wsf + 9 * M1 + 16);

    const int MTOK  = NB * SEQ;                       // 4096
    const int nQKVW = NL * QKVD * DIM;                // 3145728
    const int nPROJ = NL * DIM * DIM;                 // 1048576
    const int nW1   = NL * MLPD * DIM;                // 4194304
    const int nW2   = NL * DIM * MLPD;                // 4194304
    const size_t wcElems = (size_t)nQKVW + nPROJ + nW1 + nW2;   // 12582912
    const int big = ws_size >= ((9 * M1 + 16) * 4 + wcElems * 2);

    unsigned short* WcQ  = Wc;
    unsigned short* WcP  = Wc + nQKVW;
    unsigned short* WcW1 = Wc + nQKVW + nPROJ;
    unsigned short* WcW2 = Wc + nQKVW + nPROJ + (size_t)nW1;

    detect_kernel<<<1, 64, 0, stream>>>((const unsigned short*)ln1w, flag);
    addpos_kernel<<<(NB * SEQ * DIM) / 256, 256, 0, stream>>>(x, pos, h, flag);

    if (big) {
        wcvt_kernel<<<nQKVW / 256, 256, 0, stream>>>(qkvw, WcQ, nQKVW, flag);
        wcvt_kernel<<<nPROJ / 256, 256, 0, stream>>>(projw, WcP, nPROJ, flag);
        wcvt_kernel<<<nW1 / 256, 256, 0, stream>>>(w1, WcW1, nW1, flag);
        wcvt_kernel<<<nW2 / 256, 256, 0, stream>>>(w2, WcW2, nW2, flag);
    }

    for (int l = 0; l < NL; ++l) {
        ln_kernel<<<MTOK, 256, 0, stream>>>(h, ln1w, ln1b, (size_t)l * DIM, bn, flag);
        if (big) {
            gemm_n128_dlds_kernel<<<dim3(QKVD / 128, MTOK / 128), 256, 0, stream>>>(
                bn, WcQ, (size_t)l * QKVD * DIM, nullptr, 0, C2,
                MTOK, QKVD, DIM, 0, flag);
        } else {
            gemm_mfma_kernel<<<dim3(QKVD / 128, MTOK / 128), 256, 0, stream>>>(
                bn, qkvw, (size_t)l * QKVD * DIM, nullptr, 0, C2,
                MTOK, QKVD, DIM, 0, flag);
        }
        // fused conv+prep: reads C2, writes q->bn, Kc, Vt (no alias)
        dwqkv_kernel<<<(NB * SEQ * NH) / 4, 256, 0, stream>>>(
            C2, dww, (size_t)l * QKVD * 3, temp, (size_t)l * NH, bn, Kc, Vt, flag);
        // attn: q from bn (stride DIM), output in-place to bn (disjoint regions)
        attn_kernel<<<NB * NH * (SEQ / QT), 256, 0, stream>>>(bn, Kc, Vt, bn);
        if (big) {
            gemm_n64_dlds_kernel<<<dim3(DIM / 64, MTOK / 128, 2), 256, 0, stream>>>(
                bn, WcP, (size_t)l * DIM * DIM, nullptr, 0, h,
                MTOK, DIM, DIM, 8, flag);
        } else {
            gemm_mfma_n64_kernel<<<dim3(DIM / 64, MTOK / 128), 256, 0, stream>>>(
                bn, projw, (size_t)l * DIM * DIM, nullptr, 0, h,
                MTOK, DIM, DIM, 1, flag);
        }
        ln_kernel<<<MTOK, 256, 0, stream>>>(h, ln2w, ln2b, (size_t)l * DIM, bn, flag);
        if (big) {
            gemm_n128_dlds_kernel<<<dim3(MLPD / 128, MTOK / 128), 256, 0, stream>>>(
                bn, WcW1, (size_t)l * MLPD * DIM, b1, (size_t)l * MLPD, Mb,
                MTOK, MLPD, DIM, 2 | 4, flag);
            gemm_n64_dlds_kernel<<<dim3(DIM / 64, MTOK / 128, 2), 256, 0, stream>>>(
                Mb, WcW2, (size_t)l * DIM * MLPD, b2, (size_t)l * DIM, h,
                MTOK, DIM, MLPD, 8 | 4, flag);
        } else {
            gemm_mfma_kernel<<<dim3(MLPD / 128, MTOK / 128), 256, 0, stream>>>(
                bn, w1, (size_t)l * MLPD * DIM, b1, (size_t)l * MLPD, Mb,
                MTOK, MLPD, DIM, 2 | 4, flag);
            gemm_mfma_n64_kernel<<<dim3(DIM / 64, MTOK / 128), 256, 0, stream>>>(
                Mb, w2, (size_t)l * DIM * MLPD, b2, (size_t)l * DIM, h,
                MTOK, DIM, MLPD, 1 | 4, flag);
        }
    }

    lnf_kernel<<<MTOK, 256, 0, stream>>>(h, lnfw, lnfb, d_out, flag);
}

// Round 4
// 999.084 us; speedup vs baseline: 1.0433x; 1.0433x over previous
//
#include <hip/hip_runtime.h>

// Problem constants
#define NB   4
#define SEQ  1024
#define DIM  512
#define NH   8
#define HD   64
#define MLPD 2048
#define NL   4
#define TOPKK 256
#define QKVD 1536   // 3*DIM
#define QT   16     // queries per attention block

typedef short bh8 __attribute__((ext_vector_type(8)));
typedef float f32x4 __attribute__((ext_vector_type(4)));

// ---------- helpers ----------
__device__ __forceinline__ float b2f(unsigned short v) {
    return __uint_as_float(((unsigned)v) << 16);
}
__device__ __forceinline__ unsigned short f2b(float f) {
    unsigned u = __float_as_uint(f);
    u += 0x7FFFu + ((u >> 16) & 1u);   // RNE
    return (unsigned short)(u >> 16);
}
__device__ __forceinline__ float ldin(const void* p, size_t i, int bf) {
    return bf ? b2f(((const unsigned short*)p)[i]) : ((const float*)p)[i];
}
__device__ __forceinline__ float wave_sum(float v) {
#pragma unroll
    for (int m = 32; m; m >>= 1) v += __shfl_xor(v, m);
    return v;
}
// monotone bf16-bits -> 16-bit radix key, and inverse
__device__ __forceinline__ unsigned f2key16(unsigned short u) {
    return (u & 0x8000u) ? (unsigned)((~u) & 0xFFFFu) : (unsigned)(u | 0x8000u);
}
__device__ __forceinline__ unsigned short key16b(unsigned k) {
    return (k & 0x8000u) ? (unsigned short)(k & 0x7FFFu)
                         : (unsigned short)((~k) & 0xFFFFu);
}
// packed 2xf32 -> 2xbf16 (HW RNE)
__device__ __forceinline__ unsigned cvtpk(float a, float b) {
    unsigned r;
    asm("v_cvt_pk_bf16_f32 %0, %1, %2" : "=v"(r) : "v"(a), "v"(b));
    return r;
}
// 8 contiguous fp32 -> packed bf16x8
__device__ __forceinline__ uint4 pack8(const float* __restrict__ p) {
    uint4 r;
    r.x = (unsigned)f2b(p[0]) | ((unsigned)f2b(p[1]) << 16);
    r.y = (unsigned)f2b(p[2]) | ((unsigned)f2b(p[3]) << 16);
    r.z = (unsigned)f2b(p[4]) | ((unsigned)f2b(p[5]) << 16);
    r.w = (unsigned)f2b(p[6]) | ((unsigned)f2b(p[7]) << 16);
    return r;
}
// async 16B/lane global->LDS: LDS dest = wave-uniform base + lane*16
__device__ __forceinline__ void async16(unsigned short* lds, const unsigned short* g) {
    __builtin_amdgcn_global_load_lds(
        (const __attribute__((address_space(1))) unsigned int*)g,
        (__attribute__((address_space(3))) unsigned int*)lds, 16, 0, 0);
}

// ---------- kernels ----------

__global__ void detect_kernel(const unsigned short* __restrict__ ln1w,
                              int* __restrict__ flag) {
    if (threadIdx.x == 0 && blockIdx.x == 0)
        *flag = (ln1w[0] == 0x3F80u) ? 1 : 0;
}

// convert weight array (input dtype) -> bf16 scratch
__global__ __launch_bounds__(256) void wcvt_kernel(
    const void* __restrict__ W, unsigned short* __restrict__ out,
    int n, const int* __restrict__ dflag) {
    int bf = *dflag;
    int idx = blockIdx.x * 256 + threadIdx.x;
    if (idx < n) out[idx] = f2b(ldin(W, idx, bf));
}

__global__ __launch_bounds__(256) void addpos_kernel(
    const void* __restrict__ x, const void* __restrict__ pos,
    float* __restrict__ h, const int* __restrict__ dflag) {
    int bf = *dflag;
    int idx = blockIdx.x * 256 + threadIdx.x;
    int sd = idx & (SEQ * DIM - 1);
    h[idx] = ldin(x, idx, bf) + ldin(pos, sd, bf);
}

// layernorm over last dim (512): fp32 in, bf16 out. w/b at element offset wo.
__global__ __launch_bounds__(256) void ln_kernel(
    const float* __restrict__ in, const void* __restrict__ w,
    const void* __restrict__ bb, size_t wo, unsigned short* __restrict__ out,
    const int* __restrict__ dflag) {
    int bf = *dflag;
    __shared__ float red[4];
    int row = blockIdx.x, tid = threadIdx.x;
    int lane = tid & 63, wid = tid >> 6;
    const float* p = in + (size_t)row * DIM;
    float x0 = p[tid], x1 = p[tid + 256];
    float s = wave_sum(x0 + x1);
    if (!lane) red[wid] = s;
    __syncthreads();
    float mean = (red[0] + red[1] + red[2] + red[3]) * (1.0f / DIM);
    float d0 = x0 - mean, d1 = x1 - mean;
    float q = wave_sum(d0 * d0 + d1 * d1);
    __syncthreads();
    if (!lane) red[wid] = q;
    __syncthreads();
    float var = (red[0] + red[1] + red[2] + red[3]) * (1.0f / DIM);
    float rs = rsqrtf(var + 1e-6f);
    unsigned short* o = out + (size_t)row * DIM;
    o[tid]       = f2b(d0 * rs * ldin(w, wo + tid, bf) + ldin(bb, wo + tid, bf));
    o[tid + 256] = f2b(d1 * rs * ldin(w, wo + tid + 256, bf) + ldin(bb, wo + tid + 256, bf));
}

// final layernorm: fp32 in, output in detected dtype
__global__ __launch_bounds__(256) void lnf_kernel(
    const float* __restrict__ in, const void* __restrict__ w,
    const void* __restrict__ bb, void* __restrict__ out,
    const int* __restrict__ dflag) {
    int bf = *dflag;
    __shared__ float red[4];
    int row = blockIdx.x, tid = threadIdx.x;
    int lane = tid & 63, wid = tid >> 6;
    const float* p = in + (size_t)row * DIM;
    float x0 = p[tid], x1 = p[tid + 256];
    float s = wave_sum(x0 + x1);
    if (!lane) red[wid] = s;
    __syncthreads();
    float mean = (red[0] + red[1] + red[2] + red[3]) * (1.0f / DIM);
    float d0 = x0 - mean, d1 = x1 - mean;
    float q = wave_sum(d0 * d0 + d1 * d1);
    __syncthreads();
    if (!lane) red[wid] = q;
    __syncthreads();
    float var = (red[0] + red[1] + red[2] + red[3]) * (1.0f / DIM);
    float rs = rsqrtf(var + 1e-6f);
    float v0 = d0 * rs * ldin(w, tid, bf) + ldin(bb, tid, bf);
    float v1 = d1 * rs * ldin(w, tid + 256, bf) + ldin(bb, tid + 256, bf);
    size_t o = (size_t)row * DIM;
    if (bf) {
        ((unsigned short*)out)[o + tid]       = f2b(v0);
        ((unsigned short*)out)[o + tid + 256] = f2b(v1);
    } else {
        ((float*)out)[o + tid]       = v0;
        ((float*)out)[o + tid + 256] = v1;
    }
}

// ---- fallback GEMMs (inline fp32->bf16 pack) ----
__global__ __launch_bounds__(256) void gemm_mfma_kernel(
    const unsigned short* __restrict__ A, const void* __restrict__ W, size_t wo,
    const void* __restrict__ bias, size_t bo, void* __restrict__ C,
    int M, int N, int K, int flags, const int* __restrict__ dflag) {
    int bf = *dflag;
    __shared__ unsigned short As[128 * 32];
    __shared__ unsigned short Bs[128 * 32];
    int tid = threadIdx.x;
    int w = tid >> 6, l = tid & 63;
    int n0 = blockIdx.x * 128, m0 = blockIdx.y * 128;
    int wm = (w >> 1) * 64, wn = (w & 1) * 64;
    int lq = l & 15, lk = l >> 4;

    int srow = w * 32 + (l >> 2);
    int cb = (l & 3) * 8;
    const unsigned short* aG = A + (size_t)(m0 + srow) * K + cb;
    size_t wb = wo + (size_t)(n0 + srow) * K + cb;
    unsigned short* sA0 = &As[w * 1024 + l * 8];
    unsigned short* sA1 = &As[w * 1024 + 512 + l * 8];
    unsigned short* sB0 = &Bs[w * 1024 + l * 8];
    unsigned short* sB1 = &Bs[w * 1024 + 512 + l * 8];

    f32x4 acc[4][4];
#pragma unroll
    for (int i = 0; i < 4; ++i)
#pragma unroll
        for (int j = 0; j < 4; ++j)
            acc[i][j] = (f32x4){0.f, 0.f, 0.f, 0.f};

    for (int k0 = 0; k0 < K; k0 += 32) {
        uint4 a0 = *(const uint4*)(aG + k0);
        uint4 a1 = *(const uint4*)(aG + 16 * K + k0);
        uint4 b0, b1;
        if (bf) {
            b0 = *(const uint4*)((const unsigned short*)W + wb + k0);
            b1 = *(const uint4*)((const unsigned short*)W + wb + 16 * K + k0);
        } else {
            b0 = pack8((const float*)W + wb + k0);
            b1 = pack8((const float*)W + wb + 16 * K + k0);
        }
        __syncthreads();
        *(uint4*)sA0 = a0;
        *(uint4*)sA1 = a1;
        *(uint4*)sB0 = b0;
        *(uint4*)sB1 = b1;
        __syncthreads();
        bh8 af[4], bw[4];
#pragma unroll
        for (int i = 0; i < 4; ++i) {
            af[i] = *(const bh8*)&As[(wm + i * 16 + lq) * 32 + lk * 8];
            bw[i] = *(const bh8*)&Bs[(wn + i * 16 + lq) * 32 + lk * 8];
        }
#pragma unroll
        for (int i = 0; i < 4; ++i)
#pragma unroll
            for (int j = 0; j < 4; ++j)
                acc[i][j] = __builtin_amdgcn_mfma_f32_16x16x32_bf16(
                    af[i], bw[j], acc[i][j], 0, 0, 0);
    }

    int lr4 = lk * 4;
#pragma unroll
    for (int i = 0; i < 4; ++i) {
#pragma unroll
        for (int j = 0; j < 4; ++j) {
            int n = n0 + wn + j * 16 + lq;
            float bv = (flags & 4) ? ldin(bias, bo + n, bf) : 0.0f;
#pragma unroll
            for (int r = 0; r < 4; ++r) {
                int m = m0 + wm + i * 16 + lr4 + r;
                float v = acc[i][j][r] + bv;
                if (flags & 2) v = 0.5f * v * (1.0f + erff(v * 0.70710678118654752f));
                size_t o = (size_t)m * N + n;
                if (flags & 1) ((float*)C)[o] += v;
                else           ((unsigned short*)C)[o] = f2b(v);
            }
        }
    }
}

__global__ __launch_bounds__(256) void gemm_mfma_n64_kernel(
    const unsigned short* __restrict__ A, const void* __restrict__ W, size_t wo,
    const void* __restrict__ bias, size_t bo, void* __restrict__ C,
    int M, int N, int K, int flags, const int* __restrict__ dflag) {
    int bf = *dflag;
    __shared__ unsigned short As[128 * 32];
    __shared__ unsigned short Bs[64 * 32];
    int tid = threadIdx.x;
    int w = tid >> 6, l = tid & 63;
    int n0 = blockIdx.x * 64, m0 = blockIdx.y * 128;
    int wm = (w >> 1) * 64, wn = (w & 1) * 32;
    int lq = l & 15, lk = l >> 4;

    int srowA = w * 32 + (l >> 2);
    int cb = (l & 3) * 8;
    const unsigned short* aG = A + (size_t)(m0 + srowA) * K + cb;
    int srowB = w * 16 + (l >> 2);
    size_t wb = wo + (size_t)(n0 + srowB) * K + cb;
    unsigned short* sA0 = &As[w * 1024 + l * 8];
    unsigned short* sA1 = &As[w * 1024 + 512 + l * 8];
    unsigned short* sB0 = &Bs[w * 512 + l * 8];

    f32x4 acc[4][2];
#pragma unroll
    for (int i = 0; i < 4; ++i) {
        acc[i][0] = (f32x4){0.f, 0.f, 0.f, 0.f};
        acc[i][1] = (f32x4){0.f, 0.f, 0.f, 0.f};
    }

    for (int k0 = 0; k0 < K; k0 += 32) {
        uint4 a0 = *(const uint4*)(aG + k0);
        uint4 a1 = *(const uint4*)(aG + 16 * K + k0);
        uint4 b0;
        if (bf) b0 = *(const uint4*)((const unsigned short*)W + wb + k0);
        else    b0 = pack8((const float*)W + wb + k0);
        __syncthreads();
        *(uint4*)sA0 = a0;
        *(uint4*)sA1 = a1;
        *(uint4*)sB0 = b0;
        __syncthreads();
        bh8 af[4], bw[2];
#pragma unroll
        for (int i = 0; i < 4; ++i)
            af[i] = *(const bh8*)&As[(wm + i * 16 + lq) * 32 + lk * 8];
        bw[0] = *(const bh8*)&Bs[(wn + lq) * 32 + lk * 8];
        bw[1] = *(const bh8*)&Bs[(wn + 16 + lq) * 32 + lk * 8];
#pragma unroll
        for (int i = 0; i < 4; ++i) {
            acc[i][0] = __builtin_amdgcn_mfma_f32_16x16x32_bf16(af[i], bw[0], acc[i][0], 0, 0, 0);
            acc[i][1] = __builtin_amdgcn_mfma_f32_16x16x32_bf16(af[i], bw[1], acc[i][1], 0, 0, 0);
        }
    }

    int lr4 = lk * 4;
#pragma unroll
    for (int i = 0; i < 4; ++i) {
#pragma unroll
        for (int j = 0; j < 2; ++j) {
            int n = n0 + wn + j * 16 + lq;
            float bv = (flags & 4) ? ldin(bias, bo + n, bf) : 0.0f;
#pragma unroll
            for (int r = 0; r < 4; ++r) {
                int m = m0 + wm + i * 16 + lr4 + r;
                float v = acc[i][j][r] + bv;
                if (flags & 2) v = 0.5f * v * (1.0f + erff(v * 0.70710678118654752f));
                size_t o = (size_t)m * N + n;
                if (flags & 1) ((float*)C)[o] += v;
                else           ((unsigned short*)C)[o] = f2b(v);
            }
        }
    }
}

// ---- main-path GEMM: 128Mx64N, bf16 weights, global_load_lds staging,
// optional split-K via blockIdx.z (flags&8 = atomic fp32 +=).
// flags: 1 = plain fp32 +=, 2 = GELU->bf16, 0 = bf16 store, 4 = bias, 8 = atomic +=
__global__ __launch_bounds__(256) void gemm_n64_dlds_kernel(
    const unsigned short* __restrict__ A, const unsigned short* __restrict__ W, size_t wo,
    const void* __restrict__ bias, size_t bo, void* __restrict__ C,
    int M, int N, int K, int flags, const int* __restrict__ dflag) {
    __shared__ unsigned short As[128 * 32];
    __shared__ unsigned short Bs[64 * 32];
    int tid = threadIdx.x;
    int w = tid >> 6, l = tid & 63;
    int n0 = blockIdx.x * 64, m0 = blockIdx.y * 128;
    int kz = blockIdx.z;
    int Ks = K / (int)gridDim.z;
    int kbeg = kz * Ks, kend = kbeg + Ks;
    int wm = (w >> 1) * 64, wn = (w & 1) * 32;
    int lq = l & 15, lk = l >> 4;

    int srowA = w * 32 + (l >> 2);
    int srowB = w * 16 + (l >> 2);
    int cb = (l & 3) * 8;
    const unsigned short* aG = A + (size_t)(m0 + srowA) * K + cb;
    const unsigned short* wG = W + wo + (size_t)(n0 + srowB) * K + cb;
    unsigned short* lA0 = As + w * 1024;
    unsigned short* lA1 = As + w * 1024 + 512;
    unsigned short* lB0 = Bs + w * 512;

    f32x4 acc[4][2];
#pragma unroll
    for (int i = 0; i < 4; ++i) {
        acc[i][0] = (f32x4){0.f, 0.f, 0.f, 0.f};
        acc[i][1] = (f32x4){0.f, 0.f, 0.f, 0.f};
    }

    for (int k0 = kbeg; k0 < kend; k0 += 32) {
        __syncthreads();            // prior iter's LDS reads complete
        async16(lA0, aG + k0);
        async16(lA1, aG + 16 * K + k0);
        async16(lB0, wG + k0);
        __syncthreads();            // barrier drains vmcnt -> staged
        bh8 af[4], bw[2];
#pragma unroll
        for (int i = 0; i < 4; ++i)
            af[i] = *(const bh8*)&As[(wm + i * 16 + lq) * 32 + lk * 8];
        bw[0] = *(const bh8*)&Bs[(wn + lq) * 32 + lk * 8];
        bw[1] = *(const bh8*)&Bs[(wn + 16 + lq) * 32 + lk * 8];
#pragma unroll
        for (int i = 0; i < 4; ++i) {
            acc[i][0] = __builtin_amdgcn_mfma_f32_16x16x32_bf16(af[i], bw[0], acc[i][0], 0, 0, 0);
            acc[i][1] = __builtin_amdgcn_mfma_f32_16x16x32_bf16(af[i], bw[1], acc[i][1], 0, 0, 0);
        }
    }

    int bf = (flags & 4) ? *dflag : 0;
    int lr4 = lk * 4;
#pragma unroll
    for (int i = 0; i < 4; ++i) {
#pragma unroll
        for (int j = 0; j < 2; ++j) {
            int n = n0 + wn + j * 16 + lq;
            float bv = ((flags & 4) && kz == 0) ? ldin(bias, bo + n, bf) : 0.0f;
#pragma unroll
            for (int r = 0; r < 4; ++r) {
                int m = m0 + wm + i * 16 + lr4 + r;
                float v = acc[i][j][r] + bv;
                if (flags & 2) v = 0.5f * v * (1.0f + erff(v * 0.70710678118654752f));
                size_t o = (size_t)m * N + n;
                if (flags & 8)      atomicAdd(&((float*)C)[o], v);
                else if (flags & 1) ((float*)C)[o] += v;
                else                ((unsigned short*)C)[o] = f2b(v);
            }
        }
    }
}

// fused depthwise conv (k=3 along s) + q/k normalize + scatter.
// reads qkv (B,S,3D) bf16 pre-conv; writes: qn (B,S,D bf16, temp folded),
// Kc[bh][s][c], Vt[bh][s>>5][c][s&31]. No aliasing with input.
__global__ __launch_bounds__(256) void dwqkv_kernel(
    const unsigned short* __restrict__ in, const void* __restrict__ w, size_t wo,
    const void* __restrict__ temp, size_t to,
    unsigned short* __restrict__ qn, unsigned short* __restrict__ Kc,
    unsigned short* __restrict__ Vt, const int* __restrict__ dflag) {
    int bf = *dflag;
    int tid = threadIdx.x;
    int g = tid >> 6, c = tid & 63;
    int gid = blockIdx.x * 4 + g;          // (b*S+s)*H + h
    int h = gid & 7;
    int bs = gid >> 3;
    int s = bs & (SEQ - 1), b = bs >> 10;
    int bh = b * NH + h;
    const unsigned short* row = in + (size_t)bs * QKVD;
    float vals[3];
#pragma unroll
    for (int t = 0; t < 3; ++t) {
        int o = t * 512 + h * HD + c;
        float w0 = ldin(w, wo + o * 3 + 0, bf);
        float w1 = ldin(w, wo + o * 3 + 1, bf);
        float w2 = ldin(w, wo + o * 3 + 2, bf);
        float a = w1 * b2f(row[o]);
        if (s > 0)       a += w0 * b2f(row[o - QKVD]);
        if (s < SEQ - 1) a += w2 * b2f(row[o + QKVD]);
        vals[t] = a;
    }
    float qs = wave_sum(vals[0] * vals[0]);
    float ks = wave_sum(vals[1] * vals[1]);
    float t_ = ldin(temp, to + h, bf);
    qn[(size_t)bs * DIM + h * HD + c] = f2b(vals[0] / fmaxf(sqrtf(qs), 1e-12f) * t_);
    Kc[((size_t)bh * SEQ + s) * HD + c] = f2b(vals[1] / fmaxf(sqrtf(ks), 1e-12f));
    Vt[(((size_t)bh * 32 + (s >> 5)) * HD + c) * 32 + (s & 31)] = f2b(vals[2]);
}

// Q-tiled MFMA attention.
// v5: swapped-operand QK^T: mfma(K,Q) -> lane holds 4 consecutive KEYS of one
// q-row (col=lq). Score write = 2x cvt_pk + 1x ds_write_b64 (was 4 f2b +
// 4 ds_write_b16). Chunk4 XOR swizzle keyed by q-row (bits 1-3): b64 writes
// and b128 reads stay aligned+ordered; select phase is permutation-invariant.
// Unroll-2 load batching in QK^T (4 K loads in flight) and PV.
__global__ __launch_bounds__(256) void attn_kernel(
    const unsigned short* __restrict__ q, const unsigned short* __restrict__ Kc,
    const unsigned short* __restrict__ Vt, unsigned short* __restrict__ outp) {
    __shared__ __align__(16) unsigned short sc16[QT * 1024];

    int tid = threadIdx.x;
    int w = tid >> 6, l = tid & 63;
    int lq = l & 15, lk = l >> 4;
    int bid = blockIdx.x;
    int qt = (bid >> 3) & 63;
    int bh = ((bid >> 9) << 3) | (bid & 7);   // XCD-locality remap (bijective)
    int h = bh & 7;
    int b = bh >> 3;

    // q rows have stride DIM (written by dwqkv into a dense (B*S, D) buffer)
    const unsigned short* qp = q + (size_t)(b * SEQ + qt * QT + lq) * DIM + h * HD + lk * 8;
    bh8 aq0 = *(const bh8*)(qp);
    bh8 aq1 = *(const bh8*)(qp + 32);

    int swz = ((lq ^ (lq >> 2)) & 7) << 1;   // per-q-row chunk4 XOR (bits 1-3)

    // QK^T: wave w computes keys [w*256,(w+1)*256) for all 16 queries.
    // mfma(K,Q): lane (lq,lk) -> q-row lq, keys key0 + lk*4 .. +3.
    const unsigned short* Kbh = Kc + (size_t)bh * SEQ * HD;
    unsigned short* srowq = sc16 + lq * 1024;
    for (int kb = 0; kb < 16; kb += 2) {
        int key0 = (w * 16 + kb) * 16;
        const unsigned short* kp0 = Kbh + (size_t)(key0 + lq) * HD + lk * 8;
        const unsigned short* kp1 = kp0 + 16 * HD;
        bh8 b0 = *(const bh8*)(kp0);
        bh8 b1 = *(const bh8*)(kp0 + 32);
        bh8 b2 = *(const bh8*)(kp1);
        bh8 b3 = *(const bh8*)(kp1 + 32);
        f32x4 a0 = {0.f, 0.f, 0.f, 0.f};
        f32x4 a1 = {0.f, 0.f, 0.f, 0.f};
        a0 = __builtin_amdgcn_mfma_f32_16x16x32_bf16(b0, aq0, a0, 0, 0, 0);
        a0 = __builtin_amdgcn_mfma_f32_16x16x32_bf16(b1, aq1, a0, 0, 0, 0);
        a1 = __builtin_amdgcn_mfma_f32_16x16x32_bf16(b2, aq0, a1, 0, 0, 0);
        a1 = __builtin_amdgcn_mfma_f32_16x16x32_bf16(b3, aq1, a1, 0, 0, 0);
        int c0 = (key0 >> 2) + lk;           // chunk4 index of first 4 keys
        uint2 w0 = {cvtpk(a0[0], a0[1]), cvtpk(a0[2], a0[3])};
        uint2 w1 = {cvtpk(a1[0], a1[1]), cvtpk(a1[2], a1[3])};
        *(uint2*)&srowq[(c0 ^ swz) << 2]       = w0;
        *(uint2*)&srowq[((c0 + 4) ^ swz) << 2] = w1;
    }
    __syncthreads();

    // fused top-k select + softmax: wave w owns rows w*4..w*4+3
    for (int rr = 0; rr < 4; ++rr) {
        int row = w * 4 + rr;
        unsigned short* srow = sc16 + row * 1024;
        uint4 r0 = *(const uint4*)&srow[l * 8];
        uint4 r1 = *(const uint4*)&srow[512 + l * 8];
        unsigned wd[8] = {r0.x, r0.y, r0.z, r0.w, r1.x, r1.y, r1.z, r1.w};
        float v[16];
#pragma unroll
        for (int j = 0; j < 8; ++j) {
            v[2 * j]     = __uint_as_float(wd[j] << 16);
            v[2 * j + 1] = __uint_as_float(wd[j] & 0xFFFF0000u);
        }
        // row max (order-independent under swizzle)
        float m = v[0];
#pragma unroll
        for (int j = 1; j < 16; ++j) m = fmaxf(m, v[j]);
#pragma unroll
        for (int off = 1; off < 64; off <<= 1) m = fmaxf(m, __shfl_xor(m, off));
        m = fminf(fmaxf(m, -10000.f), 10000.f);
        // ballot binary search for kth-largest bf16 value (exact tie semantics)
        unsigned T = 0;
        for (int bit = 15; bit >= 0; --bit) {
            unsigned cand = T | (1u << bit);
            float tf = b2f(key16b(cand));
            unsigned cnt = 0;
#pragma unroll
            for (int j = 0; j < 16; ++j)
                cnt += (unsigned)__popcll(__ballot(v[j] >= tf));
            if (cnt >= TOPKK) T = cand;
        }
        float kth = b2f(key16b(T));
        // exp + sum (excluded -> exactly 0.0f)
        float ssum = 0.f;
#pragma unroll
        for (int j = 0; j < 16; ++j) {
            float a = fminf(fmaxf(v[j], -10000.f), 10000.f);
            float ev = (v[j] >= kth) ? __expf(a - m) : 0.0f;
            ssum += ev;
            v[j] = ev;
        }
#pragma unroll
        for (int off = 1; off < 64; off <<= 1) ssum += __shfl_xor(ssum, off);
        float inv = 1.0f / ssum;
        // pre-scale by 1/sum, pack to bf16 (HW RNE), write back in place
        unsigned pw[8];
#pragma unroll
        for (int j = 0; j < 8; ++j)
            pw[j] = cvtpk(v[2 * j] * inv, v[2 * j + 1] * inv);
        *(uint4*)&srow[l * 8]       = (uint4){pw[0], pw[1], pw[2], pw[3]};
        *(uint4*)&srow[512 + l * 8] = (uint4){pw[4], pw[5], pw[6], pw[7]};
    }
    __syncthreads();

    // PV (P already normalized); P fragment read applies the same chunk4 XOR
    {
        const unsigned short* Vbh = Vt + (size_t)bh * SEQ * HD;
        const unsigned short* prow = sc16 + lq * 1024;
        f32x4 oacc = {0.f, 0.f, 0.f, 0.f};
        for (int tc = 0; tc < 32; tc += 2) {
            const unsigned short* vp0 = Vbh + (size_t)tc * 2048 + (w * 16 + lq) * 32 + lk * 8;
            bh8 bv0 = *(const bh8*)(vp0);
            bh8 bv1 = *(const bh8*)(vp0 + 2048);
            bh8 ap0 = *(const bh8*)&prow[((tc * 8 + lk * 2) ^ swz) << 2];
            bh8 ap1 = *(const bh8*)&prow[(((tc + 1) * 8 + lk * 2) ^ swz) << 2];
            oacc = __builtin_amdgcn_mfma_f32_16x16x32_bf16(ap0, bv0, oacc, 0, 0, 0);
            oacc = __builtin_amdgcn_mfma_f32_16x16x32_bf16(ap1, bv1, oacc, 0, 0, 0);
        }
#pragma unroll
        for (int r = 0; r < 4; ++r) {
            int qrow = lk * 4 + r;
            outp[((size_t)(b * SEQ + qt * QT + qrow)) * DIM + h * HD + w * 16 + lq] = f2b(oacc[r]);
        }
    }
}

// ---------- host ----------
extern "C" void kernel_launch(void* const* d_in, const int* in_sizes, int n_in,
                              void* d_out, int out_size, void* d_ws, size_t ws_size,
                              hipStream_t stream) {
    (void)in_sizes; (void)n_in; (void)out_size;
    const void* x     = d_in[0];
    const void* pos   = d_in[1];
    const void* ln1w  = d_in[2];
    const void* ln1b  = d_in[3];
    const void* qkvw  = d_in[4];
    const void* dww   = d_in[5];
    const void* temp  = d_in[6];
    const void* projw = d_in[7];
    const void* ln2w  = d_in[8];
    const void* ln2b  = d_in[9];
    const void* w1    = d_in[10];
    const void* b1    = d_in[11];
    const void* w2    = d_in[12];
    const void* b2    = d_in[13];
    const void* lnfw  = d_in[14];
    const void* lnfb  = d_in[15];

    // ws layout (float units): h[0,2M) | bn@2M (ln out / q / attn out) |
    // C2@3M (qkv pre-conv / MLP mid) | Vt@6M | Kc@7M | flag@9M | Wc@(9M+16)
    float* wsf = (float*)d_ws;
    const size_t M1 = (size_t)1024 * 1024;
    float*          h    = wsf;
    unsigned short* bn   = (unsigned short*)(wsf + 2 * M1);
    unsigned short* C2   = (unsigned short*)(wsf + 3 * M1);
    unsigned short* Vt   = (unsigned short*)(wsf + 6 * M1);
    unsigned short* Kc   = (unsigned short*)(wsf + 7 * M1);
    unsigned short* Mb   = C2;
    int*            flag = (int*)(wsf + 9 * M1);
    unsigned short* Wc   = (unsigned short*)(wsf + 9 * M1 + 16);

    const int MTOK  = NB * SEQ;                       // 4096
    const int nQKVW = NL * QKVD * DIM;                // 3145728
    const int nPROJ = NL * DIM * DIM;                 // 1048576
    const int nW1   = NL * MLPD * DIM;                // 4194304
    const int nW2   = NL * DIM * MLPD;                // 4194304
    const size_t wcElems = (size_t)nQKVW + nPROJ + nW1 + nW2;   // 12582912
    const int big = ws_size >= ((9 * M1 + 16) * 4 + wcElems * 2);

    unsigned short* WcQ  = Wc;
    unsigned short* WcP  = Wc + nQKVW;
    unsigned short* WcW1 = Wc + nQKVW + nPROJ;
    unsigned short* WcW2 = Wc + nQKVW + nPROJ + (size_t)nW1;

    detect_kernel<<<1, 64, 0, stream>>>((const unsigned short*)ln1w, flag);
    addpos_kernel<<<(NB * SEQ * DIM) / 256, 256, 0, stream>>>(x, pos, h, flag);

    if (big) {
        wcvt_kernel<<<nQKVW / 256, 256, 0, stream>>>(qkvw, WcQ, nQKVW, flag);
        wcvt_kernel<<<nPROJ / 256, 256, 0, stream>>>(projw, WcP, nPROJ, flag);
        wcvt_kernel<<<nW1 / 256, 256, 0, stream>>>(w1, WcW1, nW1, flag);
        wcvt_kernel<<<nW2 / 256, 256, 0, stream>>>(w2, WcW2, nW2, flag);
    }

    for (int l = 0; l < NL; ++l) {
        ln_kernel<<<MTOK, 256, 0, stream>>>(h, ln1w, ln1b, (size_t)l * DIM, bn, flag);
        if (big) {
            gemm_n64_dlds_kernel<<<dim3(QKVD / 64, MTOK / 128, 1), 256, 0, stream>>>(
                bn, WcQ, (size_t)l * QKVD * DIM, nullptr, 0, C2,
                MTOK, QKVD, DIM, 0, flag);
        } else {
            gemm_mfma_kernel<<<dim3(QKVD / 128, MTOK / 128), 256, 0, stream>>>(
                bn, qkvw, (size_t)l * QKVD * DIM, nullptr, 0, C2,
                MTOK, QKVD, DIM, 0, flag);
        }
        // fused conv+prep: reads C2, writes q->bn, Kc, Vt (no alias)
        dwqkv_kernel<<<(NB * SEQ * NH) / 4, 256, 0, stream>>>(
            C2, dww, (size_t)l * QKVD * 3, temp, (size_t)l * NH, bn, Kc, Vt, flag);
        // attn: q from bn (stride DIM), output in-place to bn (disjoint regions)
        attn_kernel<<<NB * NH * (SEQ / QT), 256, 0, stream>>>(bn, Kc, Vt, bn);
        if (big) {
            gemm_n64_dlds_kernel<<<dim3(DIM / 64, MTOK / 128, 2), 256, 0, stream>>>(
                bn, WcP, (size_t)l * DIM * DIM, nullptr, 0, h,
                MTOK, DIM, DIM, 8, flag);
        } else {
            gemm_mfma_n64_kernel<<<dim3(DIM / 64, MTOK / 128), 256, 0, stream>>>(
                bn, projw, (size_t)l * DIM * DIM, nullptr, 0, h,
                MTOK, DIM, DIM, 1, flag);
        }
        ln_kernel<<<MTOK, 256, 0, stream>>>(h, ln2w, ln2b, (size_t)l * DIM, bn, flag);
        if (big) {
            gemm_n64_dlds_kernel<<<dim3(MLPD / 64, MTOK / 128, 1), 256, 0, stream>>>(
                bn, WcW1, (size_t)l * MLPD * DIM, b1, (size_t)l * MLPD, Mb,
                MTOK, MLPD, DIM, 2 | 4, flag);
            gemm_n64_dlds_kernel<<<dim3(DIM / 64, MTOK / 128, 2), 256, 0, stream>>>(
                Mb, WcW2, (size_t)l * DIM * MLPD, b2, (size_t)l * DIM, h,
                MTOK, DIM, MLPD, 8 | 4, flag);
        } else {
            gemm_mfma_kernel<<<dim3(MLPD / 128, MTOK / 128), 256, 0, stream>>>(
                bn, w1, (size_t)l * MLPD * DIM, b1, (size_t)l * MLPD, Mb,
                MTOK, MLPD, DIM, 2 | 4, flag);
            gemm_mfma_n64_kernel<<<dim3(DIM / 64, MTOK / 128), 256, 0, stream>>>(
                Mb, w2, (size_t)l * DIM * MLPD, b2, (size_t)l * DIM, h,
                MTOK, DIM, MLPD, 1 | 4, flag);
        }
    }

    lnf_kernel<<<MTOK, 256, 0, stream>>>(h, lnfw, lnfb, d_out, flag);
}